// Round 2
// baseline (750.439 us; speedup 1.0000x reference)
//
#include <hip/hip_runtime.h>
#include <hip/hip_cooperative_groups.h>

namespace cg = cooperative_groups;

#define N_NODES 4096
#define F_IN    512
#define NH1     8
#define F1      64   // NH1*ND1
#define C2      16
#define MAXDEG  128  // Binomial(4095,0.005): mean 20.5, max ~50; 128 unreachable

#define GEMM_BLKS 512    // 8 rows each -> 4096 rows
#define NBLK      1024   // cooperative grid: 4 blocks/CU on 256 CUs
#define READY_HI  0x5EC70000u

__device__ __forceinline__ float wave_sum(float v) {
    for (int o = 32; o >= 1; o >>= 1) v += __shfl_xor(v, o, 64);
    return v;
}

// ===========================================================================
// Fused single-launch GAT: phase1 (detect || GEMM1 || CSR-scan) -> grid.sync
// -> phase2 (attn1 + ELU + gemm2/scores2) -> grid.sync -> phase3 (attn2).
// 1024 blocks x 256 thr, 33 KB LDS, <=128 VGPR => 4 blocks/CU co-resident.
// ===========================================================================
__global__ __launch_bounds__(256, 4) void fused_gat(
        const unsigned char* __restrict__ adj,
        const float* __restrict__ x, const float* __restrict__ W1,
        const float* __restrict__ asrc, const float* __restrict__ adst,
        const float* __restrict__ W2, const float* __restrict__ a2s,
        const float* __restrict__ a2d, float* __restrict__ out,
        unsigned int* __restrict__ ready,
        unsigned short* __restrict__ neigh, int* __restrict__ deg,
        float* __restrict__ h1, float* __restrict__ es, float* __restrict__ ed,
        float* __restrict__ h2, float* __restrict__ es2, float* __restrict__ ed2) {
    __shared__ __align__(16) char smem[33024];
    const int t = threadIdx.x;
    const int wv = t >> 6;
    const int l = t & 63;
    const int bid = blockIdx.x;
    cg::grid_group grid = cg::this_grid();

    // ================= phase 1 =================
    if (bid < GEMM_BLKS) {
        // ---- GEMM1: 8 rows, 64 cols; single-buffer wt + register prefetch ----
        float* xs = (float*)smem;            // 8*512 floats = 16 KB
        float* wt = (float*)smem + 4096;     // 64*64 floats = 16 KB
        const int row0 = bid * 8;
        {
            const float4* src = (const float4*)(x + (size_t)row0 * F_IN);
            float4* dst = (float4*)xs;
            #pragma unroll
            for (int i = 0; i < 4; ++i) dst[t + i * 256] = src[t + i * 256];
        }
        const float4* w1v = (const float4*)W1;
        float4* wtv = (float4*)wt;
        #pragma unroll
        for (int i = 0; i < 4; ++i) wtv[t + i * 256] = w1v[t + i * 256];

        const int c = l;
        float a0 = 0.f, a1 = 0.f;
        for (int tile = 0; tile < 8; ++tile) {
            __syncthreads();                 // wt[tile] (+xs on tile 0) ready
            float4 pf0, pf1, pf2, pf3;
            if (tile < 7) {                  // prefetch next tile into regs
                const float4* s = w1v + (size_t)(tile + 1) * 1024;
                pf0 = s[t]; pf1 = s[t + 256]; pf2 = s[t + 512]; pf3 = s[t + 768];
            }
            const float4* xr0 = (const float4*)&xs[wv * F_IN + tile * 64];
            const float4* xr1 = (const float4*)&xs[(wv + 4) * F_IN + tile * 64];
            #pragma unroll
            for (int kk = 0; kk < 64; kk += 4) {
                float4 x0 = xr0[kk >> 2];
                float4 x1 = xr1[kk >> 2];
                float w0 = wt[(kk + 0) * 64 + c];
                float w1 = wt[(kk + 1) * 64 + c];
                float w2 = wt[(kk + 2) * 64 + c];
                float w3 = wt[(kk + 3) * 64 + c];
                a0 += x0.x * w0 + x0.y * w1 + x0.z * w2 + x0.w * w3;
                a1 += x1.x * w0 + x1.y * w1 + x1.z * w2 + x1.w * w3;
            }
            __syncthreads();                 // all reads of wt done
            if (tile < 7) {
                wtv[t] = pf0; wtv[t + 256] = pf1;
                wtv[t + 512] = pf2; wtv[t + 768] = pf3;
            }
        }
        const int n0 = row0 + wv;
        h1[(size_t)n0 * F1 + c] = a0;
        h1[(size_t)(n0 + 4) * F1 + c] = a1;
        float s0 = a0 * asrc[c], d0 = a0 * adst[c];
        float s1 = a1 * asrc[c], d1 = a1 * adst[c];
        s0 += __shfl_xor(s0, 1); s0 += __shfl_xor(s0, 2); s0 += __shfl_xor(s0, 4);
        d0 += __shfl_xor(d0, 1); d0 += __shfl_xor(d0, 2); d0 += __shfl_xor(d0, 4);
        s1 += __shfl_xor(s1, 1); s1 += __shfl_xor(s1, 2); s1 += __shfl_xor(s1, 4);
        d1 += __shfl_xor(d1, 1); d1 += __shfl_xor(d1, 2); d1 += __shfl_xor(d1, 4);
        if ((c & 7) == 0) {
            es[n0 * NH1 + (c >> 3)] = s0;
            ed[n0 * NH1 + (c >> 3)] = d0;
            es[(n0 + 4) * NH1 + (c >> 3)] = s1;
            ed[(n0 + 4) * NH1 + (c >> 3)] = d1;
        }
    } else {
        // ---- width detect (block GEMM_BLKS only), others spin on ready ----
        int w;
        if (bid == GEMM_BLKS) {
            unsigned int* cnts = (unsigned int*)(smem + 32768);  // 4 cnts + mxv
            if (t < 4) cnts[t] = 0u;
            if (t == 0) cnts[4] = 0u;
            __syncthreads();
            unsigned int c0 = 0, c1 = 0, c2n = 0, c3 = 0, m = 0;
            const uint4* p = (const uint4*)(adj) + t * 16;   // 256 B/thread
            #pragma unroll
            for (int i = 0; i < 16; ++i) {
                uint4 q = p[i];
                unsigned int wd[4] = {q.x, q.y, q.z, q.w};
                #pragma unroll
                for (int k = 0; k < 4; ++k) {
                    unsigned int v = wd[k];
                    unsigned int b0 = v & 0xffu, b1 = (v >> 8) & 0xffu;
                    unsigned int b2 = (v >> 16) & 0xffu, b3 = (v >> 24) & 0xffu;
                    if (b0) { c0++;  m = m > b0 ? m : b0; }
                    if (b1) { c1++;  m = m > b1 ? m : b1; }
                    if (b2) { c2n++; m = m > b2 ? m : b2; }
                    if (b3) { c3++;  m = m > b3 ? m : b3; }
                }
            }
            atomicAdd(&cnts[0], c0); atomicAdd(&cnts[1], c1);
            atomicAdd(&cnts[2], c2n); atomicAdd(&cnts[3], c3);
            atomicMax(&cnts[4], m);
            __syncthreads();
            unsigned int n0c = cnts[0], n1c = cnts[1], n2c = cnts[2],
                         n3c = cnts[3], mx = cnts[4];
            if (n1c + n2c + n3c == 0u)            w = 4;  // int32 {0,1}
            else if (n0c == 0u && n1c == 0u)      w = 4;  // fp32 {0,1.0f}
            else if (n0c == 0u && n2c == 0u)      w = 2;  // f16 1.0
            else if (mx <= 1u)                    w = 1;  // bool/uint8
            else                                  w = 2;  // bf16 1.0
            if (t == 0)
                __hip_atomic_store(ready, READY_HI | (unsigned int)w,
                                   __ATOMIC_RELEASE, __HIP_MEMORY_SCOPE_AGENT);
        } else {
            unsigned int v;
            while ((( v = __hip_atomic_load(ready, __ATOMIC_ACQUIRE,
                                            __HIP_MEMORY_SCOPE_AGENT)) & 0xffff0000u)
                   != READY_HI)
                __builtin_amdgcn_s_sleep(8);
            w = (int)(v & 0xffu);
        }
        // ---- CSR scan: 8 rows/block, 2 rows/wave (wave-synchronous) ----
        int* cnt = (int*)(smem + 32832) + wv;
        const int rbase = (bid - GEMM_BLKS) * 8 + wv * 2;
        for (int rr = 0; rr < 2; ++rr) {
            const int row = rbase + rr;
            if (l == 0) *cnt = 0;            // same-wave DS ops are in-order
            unsigned short* outp = neigh + (size_t)row * MAXDEG;
            if (w == 1) {
                const uint4* p = (const uint4*)(adj + (size_t)row * N_NODES);
                uint4 v[4];
                #pragma unroll
                for (int i = 0; i < 4; ++i) v[i] = p[l + 64 * i];
                #pragma unroll
                for (int i = 0; i < 4; ++i) {
                    if ((v[i].x | v[i].y | v[i].z | v[i].w) == 0u) continue;
                    unsigned int wd[4] = {v[i].x, v[i].y, v[i].z, v[i].w};
                    int base = (l + 64 * i) * 16;
                    for (int q = 0; q < 4; ++q) {
                        unsigned int word = wd[q];
                        for (int bb = 0; bb < 4; ++bb) {
                            if ((word >> (8 * bb)) & 0xffu) {
                                int pos = atomicAdd(cnt, 1);
                                if (pos < MAXDEG) outp[pos] = (unsigned short)(base + q * 4 + bb);
                            }
                        }
                    }
                }
            } else if (w == 2) {
                const uint4* p = (const uint4*)(adj + (size_t)row * N_NODES * 2);
                uint4 v[8];
                #pragma unroll
                for (int i = 0; i < 8; ++i) v[i] = p[l + 64 * i];
                #pragma unroll
                for (int i = 0; i < 8; ++i) {
                    if ((v[i].x | v[i].y | v[i].z | v[i].w) == 0u) continue;
                    unsigned int wd[4] = {v[i].x, v[i].y, v[i].z, v[i].w};
                    int base = (l + 64 * i) * 8;
                    for (int q = 0; q < 4; ++q) {
                        unsigned int word = wd[q];
                        if (word & 0xffffu) {
                            int pos = atomicAdd(cnt, 1);
                            if (pos < MAXDEG) outp[pos] = (unsigned short)(base + q * 2);
                        }
                        if (word >> 16) {
                            int pos = atomicAdd(cnt, 1);
                            if (pos < MAXDEG) outp[pos] = (unsigned short)(base + q * 2 + 1);
                        }
                    }
                }
            } else {
                const uint4* p = (const uint4*)(adj + (size_t)row * N_NODES * 4);
                #pragma unroll
                for (int b = 0; b < 2; ++b) {
                    uint4 v[8];
                    #pragma unroll
                    for (int i = 0; i < 8; ++i) v[i] = p[l + 64 * (b * 8 + i)];
                    #pragma unroll
                    for (int i = 0; i < 8; ++i) {
                        if ((v[i].x | v[i].y | v[i].z | v[i].w) == 0u) continue;
                        unsigned int wd[4] = {v[i].x, v[i].y, v[i].z, v[i].w};
                        int base = (l + 64 * (b * 8 + i)) * 4;
                        for (int q = 0; q < 4; ++q) {
                            if (wd[q]) {
                                int pos = atomicAdd(cnt, 1);
                                if (pos < MAXDEG) outp[pos] = (unsigned short)(base + q);
                            }
                        }
                    }
                }
            }
            if (l == 0) deg[row] = min(*cnt, MAXDEG);
        }
    }

    __threadfence();
    grid.sync();
    __threadfence();

    // ================= phase 2: attn1 + ELU + gemm2/scores2 =================
    unsigned short* list = (unsigned short*)smem + wv * MAXDEG;  // [0,1024)
    float* arow = (float*)(smem + 1024) + wv * 64;               // [1024,2048)
    float* pw   = (float*)(smem + 2048) + wv * 576;              // [2048,11264)
    const int i = bid * 4 + wv;
    const int hq = l >> 3;
    const int K = deg[i];
    {
        const unsigned short* lst = neigh + (size_t)i * MAXDEG;
        for (int j = l; j < MAXDEG; j += 64) list[j] = (j < K) ? lst[j] : (unsigned short)0;
    }
    __builtin_amdgcn_wave_barrier();

    float s2, d2;   // kept for phase 3 (same wave owns node i)
    {
        float plsum[NH1];
        #pragma unroll
        for (int h = 0; h < NH1; ++h) plsum[h] = 0.f;
        const float4 e0 = *(const float4*)(es + (size_t)i * NH1);
        const float4 e1 = *(const float4*)(es + (size_t)i * NH1 + 4);
        const float esi[NH1] = {e0.x, e0.y, e0.z, e0.w, e1.x, e1.y, e1.z, e1.w};
        float acc = 0.f;

        for (int t0 = 0; t0 < K; t0 += 64) {
            const int tc = min(64, K - t0);
            const bool valid = l < tc;
            const int j = valid ? (int)list[t0 + l] : 0;
            const float4 d0v = *(const float4*)(ed + (size_t)j * NH1);
            const float4 d1v = *(const float4*)(ed + (size_t)j * NH1 + 4);
            const float edv[NH1] = {d0v.x, d0v.y, d0v.z, d0v.w,
                                    d1v.x, d1v.y, d1v.z, d1v.w};
            #pragma unroll
            for (int h = 0; h < NH1; ++h) {
                float v = esi[h] + edv[h];
                v = (v >= 0.f) ? v : 0.2f * v;   // LeakyReLU(0.2)
                float p = valid ? __expf(v) : 0.f;  // no max-shift: |v|<~4
                plsum[h] += p;
                pw[l * 9 + h] = p;
            }
            __builtin_amdgcn_wave_barrier();
            const int tcPad = (tc + 7) & ~7;
            for (int u = 0; u < tcPad; u += 8) {
                #pragma unroll
                for (int vv2 = 0; vv2 < 8; ++vv2) {
                    int jn = (int)list[t0 + u + vv2];
                    acc += pw[(u + vv2) * 9 + hq] * h1[(size_t)jn * F1 + l];
                }
            }
            __builtin_amdgcn_wave_barrier();
        }
        float lsum[NH1];
        #pragma unroll
        for (int h = 0; h < NH1; ++h) lsum[h] = wave_sum(plsum[h]);
        float o = acc / lsum[hq];
        float a1v = (o > 0.f) ? o : (__expf(o) - 1.f);  // ELU

        arow[l] = a1v;
        __builtin_amdgcn_wave_barrier();
        const int cc = l & 15;
        const int kg = l >> 4;
        float hacc = 0.f;
        #pragma unroll
        for (int k = 0; k < 16; ++k)
            hacc += arow[kg * 16 + k] * W2[(kg * 16 + k) * C2 + cc];
        hacc += __shfl_xor(hacc, 16);
        hacc += __shfl_xor(hacc, 32);
        if (l < C2) h2[(size_t)i * C2 + l] = hacc;
        s2 = hacc * a2s[cc];
        d2 = hacc * a2d[cc];
        s2 += __shfl_xor(s2, 1); s2 += __shfl_xor(s2, 2);
        s2 += __shfl_xor(s2, 4); s2 += __shfl_xor(s2, 8);
        d2 += __shfl_xor(d2, 1); d2 += __shfl_xor(d2, 2);
        d2 += __shfl_xor(d2, 4); d2 += __shfl_xor(d2, 8);
        if (l == 0) { es2[i] = s2; ed2[i] = d2; }
    }

    __threadfence();
    grid.sync();
    __threadfence();

    // ================= phase 3: attn2 (reuses list, K, s2) =================
    {
        float* pb = (float*)(smem + 1024) + wv * 64;   // overlays dead arow
        const int c4 = l & 15;
        const int g4 = l >> 4;
        float plsum2 = 0.f, acc2 = 0.f;
        const float esi2 = s2;   // wave-uniform from phase 2
        for (int t0 = 0; t0 < K; t0 += 64) {
            const int tc = min(64, K - t0);
            const bool valid = l < tc;
            const int j = valid ? (int)list[t0 + l] : 0;
            float v = esi2 + ed2[j];
            v = (v >= 0.f) ? v : 0.2f * v;
            float p = valid ? __expf(v) : 0.f;
            plsum2 += p;
            pb[l] = p;
            __builtin_amdgcn_wave_barrier();
            const int tcPad = (tc + 3) & ~3;
            for (int u = g4; u < tcPad; u += 4) {
                int jn = (int)list[t0 + u];
                acc2 += pb[u] * h2[(size_t)jn * C2 + c4];
            }
            __builtin_amdgcn_wave_barrier();
        }
        float lsum2 = wave_sum(plsum2);
        acc2 += __shfl_xor(acc2, 16);
        acc2 += __shfl_xor(acc2, 32);
        if (l < C2) out[(size_t)i * C2 + l] = acc2 / lsum2;
    }
}

// ===========================================================================
// Legacy 4-kernel path (round-1 validated, verbatim) — fallback if the
// cooperative launch is rejected (e.g. residency).
// ===========================================================================
__global__ void detect_width_kernel(const unsigned char* __restrict__ adj,
                                    int* __restrict__ flag) {
    __shared__ unsigned int cnts[4];
    __shared__ unsigned int mxv;
    int t = threadIdx.x;
    if (t < 4) cnts[t] = 0u;
    if (t == 0) mxv = 0u;
    __syncthreads();
    unsigned int c0 = 0, c1 = 0, c2 = 0, c3 = 0, m = 0;
    const uint4* p = (const uint4*)(adj) + t * 16;
    #pragma unroll
    for (int i = 0; i < 16; ++i) {
        uint4 q = p[i];
        unsigned int wd[4] = {q.x, q.y, q.z, q.w};
        #pragma unroll
        for (int k = 0; k < 4; ++k) {
            unsigned int v = wd[k];
            unsigned int b0 = v & 0xffu, b1 = (v >> 8) & 0xffu;
            unsigned int b2 = (v >> 16) & 0xffu, b3 = (v >> 24) & 0xffu;
            if (b0) { c0++; m = m > b0 ? m : b0; }
            if (b1) { c1++; m = m > b1 ? m : b1; }
            if (b2) { c2++; m = m > b2 ? m : b2; }
            if (b3) { c3++; m = m > b3 ? m : b3; }
        }
    }
    atomicAdd(&cnts[0], c0); atomicAdd(&cnts[1], c1);
    atomicAdd(&cnts[2], c2); atomicAdd(&cnts[3], c3);
    atomicMax(&mxv, m);
    __syncthreads();
    if (t == 0) {
        int w;
        if (cnts[1] + cnts[2] + cnts[3] == 0u)      w = 4;
        else if (cnts[0] == 0u && cnts[1] == 0u)    w = 4;
        else if (cnts[0] == 0u && cnts[2] == 0u)    w = 2;
        else if (mxv <= 1u)                          w = 1;
        else                                         w = 2;
        *flag = w;
    }
}

__global__ __launch_bounds__(256) void frontend_kernel(
        const unsigned char* __restrict__ adj, const int* __restrict__ flag,
        unsigned short* __restrict__ neigh, int* __restrict__ deg,
        const float* __restrict__ x, const float* __restrict__ W1,
        const float* __restrict__ asrc, const float* __restrict__ adst,
        float* __restrict__ h1, float* __restrict__ es, float* __restrict__ ed) {
    __shared__ __align__(16) float smem[4096 + 2 * 4096];
    __shared__ int scnt[4];
    const int t = threadIdx.x;
    const int wv = t >> 6;
    const int l = t & 63;

    if (blockIdx.x < GEMM_BLKS) {
        float* xs  = smem;
        float* wt0 = smem + 4096;
        float* wt1 = smem + 8192;
        const int row0 = blockIdx.x * 8;
        {
            const float4* src = (const float4*)(x + (size_t)row0 * F_IN);
            float4* dst = (float4*)xs;
            #pragma unroll
            for (int i = 0; i < 4; ++i) dst[t + i * 256] = src[t + i * 256];
        }
        const float4* w1v = (const float4*)W1;
        {
            float4* d = (float4*)wt0;
            #pragma unroll
            for (int i = 0; i < 4; ++i) d[t + i * 256] = w1v[t + i * 256];
        }
        const int c = t & 63;
        const int rq = t >> 6;
        float a0 = 0.f, a1 = 0.f;
        float* wcur = wt0;
        float* wnxt = wt1;
        for (int tile = 0; tile < 8; ++tile) {
            __syncthreads();
            float4 pf0, pf1, pf2, pf3;
            if (tile < 7) {
                const float4* s = w1v + (size_t)(tile + 1) * 1024;
                pf0 = s[t]; pf1 = s[t + 256]; pf2 = s[t + 512]; pf3 = s[t + 768];
            }
            const float4* xr0 = (const float4*)&xs[rq * F_IN + tile * 64];
            const float4* xr1 = (const float4*)&xs[(rq + 4) * F_IN + tile * 64];
            #pragma unroll
            for (int kk = 0; kk < 64; kk += 4) {
                float4 x0 = xr0[kk >> 2];
                float4 x1 = xr1[kk >> 2];
                float w0 = wcur[(kk + 0) * 64 + c];
                float w1 = wcur[(kk + 1) * 64 + c];
                float w2 = wcur[(kk + 2) * 64 + c];
                float w3 = wcur[(kk + 3) * 64 + c];
                a0 += x0.x * w0 + x0.y * w1 + x0.z * w2 + x0.w * w3;
                a1 += x1.x * w0 + x1.y * w1 + x1.z * w2 + x1.w * w3;
            }
            if (tile < 7) {
                float4* d = (float4*)wnxt;
                d[t] = pf0; d[t + 256] = pf1; d[t + 512] = pf2; d[t + 768] = pf3;
            }
            float* tmp = wcur; wcur = wnxt; wnxt = tmp;
        }
        const int n0 = row0 + rq;
        h1[(size_t)n0 * F1 + c] = a0;
        h1[(size_t)(n0 + 4) * F1 + c] = a1;
        float s0 = a0 * asrc[c], d0 = a0 * adst[c];
        float s1 = a1 * asrc[c], d1 = a1 * adst[c];
        s0 += __shfl_xor(s0, 1); s0 += __shfl_xor(s0, 2); s0 += __shfl_xor(s0, 4);
        d0 += __shfl_xor(d0, 1); d0 += __shfl_xor(d0, 2); d0 += __shfl_xor(d0, 4);
        s1 += __shfl_xor(s1, 1); s1 += __shfl_xor(s1, 2); s1 += __shfl_xor(s1, 4);
        d1 += __shfl_xor(d1, 1); d1 += __shfl_xor(d1, 2); d1 += __shfl_xor(d1, 4);
        if ((c & 7) == 0) {
            es[n0 * NH1 + (c >> 3)] = s0;
            ed[n0 * NH1 + (c >> 3)] = d0;
            es[(n0 + 4) * NH1 + (c >> 3)] = s1;
            ed[(n0 + 4) * NH1 + (c >> 3)] = d1;
        }
    } else {
        const int row = (blockIdx.x - GEMM_BLKS) * 4 + wv;
        int* cnt = scnt + wv;
        if (l == 0) *cnt = 0;
        const int w = *flag;
        unsigned short* outp = neigh + (size_t)row * MAXDEG;
        if (w == 1) {
            const uint4* p = (const uint4*)(adj + (size_t)row * N_NODES);
            uint4 v[4];
            #pragma unroll
            for (int i = 0; i < 4; ++i) v[i] = p[l + 64 * i];
            #pragma unroll
            for (int i = 0; i < 4; ++i) {
                if ((v[i].x | v[i].y | v[i].z | v[i].w) == 0u) continue;
                unsigned int wd[4] = {v[i].x, v[i].y, v[i].z, v[i].w};
                int base = (l + 64 * i) * 16;
                for (int q = 0; q < 4; ++q) {
                    unsigned int word = wd[q];
                    for (int bb = 0; bb < 4; ++bb) {
                        if ((word >> (8 * bb)) & 0xffu) {
                            int pos = atomicAdd(cnt, 1);
                            if (pos < MAXDEG) outp[pos] = (unsigned short)(base + q * 4 + bb);
                        }
                    }
                }
            }
        } else if (w == 2) {
            const uint4* p = (const uint4*)(adj + (size_t)row * N_NODES * 2);
            uint4 v[8];
            #pragma unroll
            for (int i = 0; i < 8; ++i) v[i] = p[l + 64 * i];
            #pragma unroll
            for (int i = 0; i < 8; ++i) {
                if ((v[i].x | v[i].y | v[i].z | v[i].w) == 0u) continue;
                unsigned int wd[4] = {v[i].x, v[i].y, v[i].z, v[i].w};
                int base = (l + 64 * i) * 8;
                for (int q = 0; q < 4; ++q) {
                    unsigned int word = wd[q];
                    if (word & 0xffffu) {
                        int pos = atomicAdd(cnt, 1);
                        if (pos < MAXDEG) outp[pos] = (unsigned short)(base + q * 2);
                    }
                    if (word >> 16) {
                        int pos = atomicAdd(cnt, 1);
                        if (pos < MAXDEG) outp[pos] = (unsigned short)(base + q * 2 + 1);
                    }
                }
            }
        } else {
            const uint4* p = (const uint4*)(adj + (size_t)row * N_NODES * 4);
            #pragma unroll
            for (int b = 0; b < 2; ++b) {
                uint4 v[8];
                #pragma unroll
                for (int i = 0; i < 8; ++i) v[i] = p[l + 64 * (b * 8 + i)];
                #pragma unroll
                for (int i = 0; i < 8; ++i) {
                    if ((v[i].x | v[i].y | v[i].z | v[i].w) == 0u) continue;
                    unsigned int wd[4] = {v[i].x, v[i].y, v[i].z, v[i].w};
                    int base = (l + 64 * (b * 8 + i)) * 4;
                    for (int q = 0; q < 4; ++q) {
                        if (wd[q]) {
                            int pos = atomicAdd(cnt, 1);
                            if (pos < MAXDEG) outp[pos] = (unsigned short)(base + q);
                        }
                    }
                }
            }
        }
        if (l == 0) deg[row] = min(*cnt, MAXDEG);
    }
}

__global__ __launch_bounds__(256) void attn1_kernel(
        const unsigned short* __restrict__ neigh, const int* __restrict__ deg,
        const float* __restrict__ h1, const float* __restrict__ es,
        const float* __restrict__ ed, const float* __restrict__ W2,
        const float* __restrict__ a2s, const float* __restrict__ a2d,
        float* __restrict__ h2, float* __restrict__ es2, float* __restrict__ ed2) {
    __shared__ unsigned short listA[4 * MAXDEG];
    __shared__ float arowA[4 * 64];
    __shared__ float pbufA[4 * 576];
    const int t = threadIdx.x;
    const int wv = t >> 6;
    const int l = t & 63;
    const int i = blockIdx.x * 4 + wv;
    unsigned short* list = listA + wv * MAXDEG;
    float* arow = arowA + wv * 64;
    float* pw   = pbufA + wv * 576;
    const int hq = l >> 3;

    const int K = deg[i];
    const unsigned short* lst = neigh + (size_t)i * MAXDEG;
    for (int j = l; j < MAXDEG; j += 64) list[j] = (j < K) ? lst[j] : (unsigned short)0;
    __builtin_amdgcn_wave_barrier();

    float plsum[NH1];
    #pragma unroll
    for (int h = 0; h < NH1; ++h) plsum[h] = 0.f;
    const float4 e0 = *(const float4*)(es + (size_t)i * NH1);
    const float4 e1 = *(const float4*)(es + (size_t)i * NH1 + 4);
    const float esi[NH1] = {e0.x, e0.y, e0.z, e0.w, e1.x, e1.y, e1.z, e1.w};
    float acc = 0.f;

    for (int t0 = 0; t0 < K; t0 += 64) {
        const int tc = min(64, K - t0);
        const bool valid = l < tc;
        const int j = valid ? (int)list[t0 + l] : 0;
        const float4 d0 = *(const float4*)(ed + (size_t)j * NH1);
        const float4 d1 = *(const float4*)(ed + (size_t)j * NH1 + 4);
        const float edv[NH1] = {d0.x, d0.y, d0.z, d0.w, d1.x, d1.y, d1.z, d1.w};
        #pragma unroll
        for (int h = 0; h < NH1; ++h) {
            float v = esi[h] + edv[h];
            v = (v >= 0.f) ? v : 0.2f * v;
            float p = valid ? __expf(v) : 0.f;
            plsum[h] += p;
            pw[l * 9 + h] = p;
        }
        __builtin_amdgcn_wave_barrier();
        const int tcPad = (tc + 7) & ~7;
        for (int u = 0; u < tcPad; u += 8) {
            #pragma unroll
            for (int vv = 0; vv < 8; ++vv) {
                int jn = (int)list[t0 + u + vv];
                acc += pw[(u + vv) * 9 + hq] * h1[(size_t)jn * F1 + l];
            }
        }
        __builtin_amdgcn_wave_barrier();
    }
    float lsum[NH1];
    #pragma unroll
    for (int h = 0; h < NH1; ++h) lsum[h] = wave_sum(plsum[h]);
    float o = acc / lsum[hq];
    float a1v = (o > 0.f) ? o : (__expf(o) - 1.f);

    arow[l] = a1v;
    __builtin_amdgcn_wave_barrier();
    const int cc = l & 15;
    const int kg = l >> 4;
    float hacc = 0.f;
    #pragma unroll
    for (int k = 0; k < 16; ++k)
        hacc += arow[kg * 16 + k] * W2[(kg * 16 + k) * C2 + cc];
    hacc += __shfl_xor(hacc, 16);
    hacc += __shfl_xor(hacc, 32);
    if (l < C2) h2[(size_t)i * C2 + l] = hacc;
    float s2 = hacc * a2s[cc];
    float d2 = hacc * a2d[cc];
    s2 += __shfl_xor(s2, 1); s2 += __shfl_xor(s2, 2);
    s2 += __shfl_xor(s2, 4); s2 += __shfl_xor(s2, 8);
    d2 += __shfl_xor(d2, 1); d2 += __shfl_xor(d2, 2);
    d2 += __shfl_xor(d2, 4); d2 += __shfl_xor(d2, 8);
    if (l == 0) { es2[i] = s2; ed2[i] = d2; }
}

__global__ __launch_bounds__(256) void attn2_kernel(
        const unsigned short* __restrict__ neigh, const int* __restrict__ deg,
        const float* __restrict__ h2, const float* __restrict__ es2,
        const float* __restrict__ ed2, float* __restrict__ out) {
    __shared__ unsigned short listA[4 * MAXDEG];
    __shared__ float pbufA[4 * 64];
    const int t = threadIdx.x;
    const int wv = t >> 6;
    const int l = t & 63;
    const int i = blockIdx.x * 4 + wv;
    unsigned short* list = listA + wv * MAXDEG;
    float* pb = pbufA + wv * 64;
    const int c = l & 15;
    const int g = l >> 4;

    const int K = deg[i];
    const unsigned short* lst = neigh + (size_t)i * MAXDEG;
    for (int j = l; j < MAXDEG; j += 64) list[j] = (j < K) ? lst[j] : (unsigned short)0;
    __builtin_amdgcn_wave_barrier();

    float plsum = 0.f, acc = 0.f;
    const float esi = es2[i];
    for (int t0 = 0; t0 < K; t0 += 64) {
        const int tc = min(64, K - t0);
        const bool valid = l < tc;
        const int j = valid ? (int)list[t0 + l] : 0;
        float v = esi + ed2[j];
        v = (v >= 0.f) ? v : 0.2f * v;
        float p = valid ? __expf(v) : 0.f;
        plsum += p;
        pb[l] = p;
        __builtin_amdgcn_wave_barrier();
        const int tcPad = (tc + 3) & ~3;
        for (int u = g; u < tcPad; u += 4) {
            int jn = (int)list[t0 + u];
            acc += pb[u] * h2[(size_t)jn * C2 + c];
        }
        __builtin_amdgcn_wave_barrier();
    }
    float lsum = wave_sum(plsum);
    acc += __shfl_xor(acc, 16);
    acc += __shfl_xor(acc, 32);
    if (l < C2) out[(size_t)i * C2 + l] = acc / lsum;
}

extern "C" void kernel_launch(void* const* d_in, const int* in_sizes, int n_in,
                              void* d_out, int out_size, void* d_ws, size_t ws_size,
                              hipStream_t stream) {
    const float* x           = (const float*)d_in[0];
    const unsigned char* adj = (const unsigned char*)d_in[1];
    const float* W1          = (const float*)d_in[2];
    const float* a1src       = (const float*)d_in[3];
    const float* a1dst       = (const float*)d_in[4];
    const float* W2          = (const float*)d_in[5];
    const float* a2src       = (const float*)d_in[6];
    const float* a2dst       = (const float*)d_in[7];
    float* out = (float*)d_out;

    // workspace layout (~2.6 MB), all offsets 256B-aligned
    char* ws = (char*)d_ws;
    size_t off = 0;
    unsigned int* ready = (unsigned int*)(ws + off);  off += 256;  // also legacy flag
    unsigned short* neigh = (unsigned short*)(ws + off);
    off += (size_t)N_NODES * MAXDEG * 2;              // 1 MB
    int* deg = (int*)(ws + off);                      off += (size_t)N_NODES * 4;
    float* h1 = (float*)(ws + off);                   off += (size_t)N_NODES * F1 * 4;
    float* es1 = (float*)(ws + off);                  off += (size_t)N_NODES * NH1 * 4;
    float* ed1 = (float*)(ws + off);                  off += (size_t)N_NODES * NH1 * 4;
    float* h2 = (float*)(ws + off);                   off += (size_t)N_NODES * C2 * 4;
    float* es2 = (float*)(ws + off);                  off += (size_t)N_NODES * 4;
    float* ed2 = (float*)(ws + off);                  off += (size_t)N_NODES * 4;

    void* args[] = { (void*)&adj, (void*)&x, (void*)&W1, (void*)&a1src, (void*)&a1dst,
                     (void*)&W2, (void*)&a2src, (void*)&a2dst, (void*)&out,
                     (void*)&ready, (void*)&neigh, (void*)&deg,
                     (void*)&h1, (void*)&es1, (void*)&ed1,
                     (void*)&h2, (void*)&es2, (void*)&ed2 };
    hipError_t err = hipLaunchCooperativeKernel((const void*)fused_gat,
                                                dim3(NBLK), dim3(256),
                                                args, 0, stream);
    if (err != hipSuccess) {
        // Fallback: validated 4-kernel path
        int* flag = (int*)ready;
        hipLaunchKernelGGL(detect_width_kernel, dim3(1), dim3(256), 0, stream, adj, flag);
        hipLaunchKernelGGL(frontend_kernel, dim3(GEMM_BLKS + N_NODES / 4), dim3(256), 0, stream,
                           adj, flag, neigh, deg, x, W1, a1src, a1dst, h1, es1, ed1);
        hipLaunchKernelGGL(attn1_kernel, dim3(N_NODES / 4), dim3(256), 0, stream,
                           neigh, deg, h1, es1, ed1, W2, a2src, a2dst, h2, es2, ed2);
        hipLaunchKernelGGL(attn2_kernel, dim3(N_NODES / 4), dim3(256), 0, stream,
                           neigh, deg, h2, es2, ed2, out);
    }
}

// Round 3
// 142.202 us; speedup vs baseline: 5.2773x; 5.2773x over previous
//
#include <hip/hip_runtime.h>

#define N_NODES 4096
#define F_IN    512
#define NH1     8
#define F1      64   // NH1*ND1
#define C2      16
#define MAXDEG  128  // Binomial(4095,0.005): mean 20.5, max ~50; 128 unreachable

#define GEMM_BLKS 256    // 16 rows each -> 4096 rows
#define SCAN_BLKS 1024   // 4 rows each (1 row/wave)

__device__ __forceinline__ float wave_sum(float v) {
    for (int o = 32; o >= 1; o >>= 1) v += __shfl_xor(v, o, 64);
    return v;
}

// ---------------------------------------------------------------------------
// Per-wave adjacency element-width detection from the first 4 KB of adj.
// Same byte-position classification rules as the R1/R4/R6/R12/R13-validated
// one-block kernel, reduced with wave ballots instead of LDS atomics.
// Self-loop at adj[0][0] guarantees >=1 nonzero for every width. Wave-uniform.
// ---------------------------------------------------------------------------
__device__ __forceinline__ int detect_width_wave(const unsigned char* __restrict__ adj,
                                                 int l) {
    bool nz0 = false, nz1 = false, nz2 = false, nz3 = false;
    unsigned int mx = 0u;
    const uint4* p = (const uint4*)adj;
    #pragma unroll
    for (int i = 0; i < 4; ++i) {          // 64 lanes * 4 * 16B = 4 KB
        uint4 q = p[l + 64 * i];
        unsigned int wd[4] = {q.x, q.y, q.z, q.w};
        #pragma unroll
        for (int k = 0; k < 4; ++k) {
            unsigned int v = wd[k];
            unsigned int b0 = v & 0xffu, b1 = (v >> 8) & 0xffu;
            unsigned int b2 = (v >> 16) & 0xffu, b3 = (v >> 24) & 0xffu;
            if (b0) { nz0 = true; mx = mx > b0 ? mx : b0; }
            if (b1) { nz1 = true; mx = mx > b1 ? mx : b1; }
            if (b2) { nz2 = true; mx = mx > b2 ? mx : b2; }
            if (b3) { nz3 = true; mx = mx > b3 ? mx : b3; }
        }
    }
    const bool a0 = __any(nz0), a1 = __any(nz1), a2 = __any(nz2), a3 = __any(nz3);
    const bool big = __any(mx > 1u);
    if (!a1 && !a2 && !a3) return 4;   // int32 {0,1}: only byte 0 of each dword
    if (!a0 && !a1)        return 4;   // fp32 1.0f: bytes 2,3
    if (!a0 && !a2)        return 2;   // f16 1.0: odd bytes only
    if (!big)              return 1;   // bool/uint8 {0,1}
    return 2;                          // bf16 1.0
}

// ---------------------------------------------------------------------------
// Fused front-end:
//   blocks [0, GEMM_BLKS):   GEMM1 (+fused es/ed), 16 rows/block, 4 out/thread
//                            (halves LDS-BW per FMA vs 2 out/thread),
//                            single-buffer wt + register prefetch.
//   blocks [GEMM_BLKS, ...): CSR row scan, 1 row/wave, per-wave width detect
//                            (detect kernel eliminated).
// ---------------------------------------------------------------------------
__global__ __launch_bounds__(256) void frontend_kernel(
        const unsigned char* __restrict__ adj,
        unsigned short* __restrict__ neigh, int* __restrict__ deg,
        const float* __restrict__ x, const float* __restrict__ W1,
        const float* __restrict__ asrc, const float* __restrict__ adst,
        float* __restrict__ h1, float* __restrict__ es, float* __restrict__ ed) {
    __shared__ __align__(16) float smem[8192 + 4096];  // xs 32 KB + wt 16 KB
    __shared__ int scnt[4];
    const int t = threadIdx.x;
    const int wv = t >> 6;
    const int l = t & 63;

    if (blockIdx.x < GEMM_BLKS) {
        // ---- GEMM1: rows row0..row0+15, cols 0..63 ----
        float* xs = smem;            // 16*512 floats
        float* wt = smem + 8192;     // 64*64 floats
        const int row0 = blockIdx.x * 16;
        {
            const float4* src = (const float4*)(x + (size_t)row0 * F_IN);
            float4* dst = (float4*)xs;
            #pragma unroll
            for (int i = 0; i < 8; ++i) dst[t + i * 256] = src[t + i * 256];
        }
        const float4* w1v = (const float4*)W1;
        float4* wtv = (float4*)wt;
        #pragma unroll
        for (int i = 0; i < 4; ++i) wtv[t + i * 256] = w1v[t + i * 256];

        const int c = l;
        float a0 = 0.f, a1 = 0.f, a2 = 0.f, a3 = 0.f;
        for (int tile = 0; tile < 8; ++tile) {
            __syncthreads();                 // wt[tile] (+xs on tile 0) ready
            float4 pf0, pf1, pf2, pf3;
            if (tile < 7) {                  // prefetch next tile into regs
                const float4* s = w1v + (size_t)(tile + 1) * 1024;
                pf0 = s[t]; pf1 = s[t + 256]; pf2 = s[t + 512]; pf3 = s[t + 768];
            }
            const float4* xr0 = (const float4*)&xs[(wv     ) * F_IN + tile * 64];
            const float4* xr1 = (const float4*)&xs[(wv +  4) * F_IN + tile * 64];
            const float4* xr2 = (const float4*)&xs[(wv +  8) * F_IN + tile * 64];
            const float4* xr3 = (const float4*)&xs[(wv + 12) * F_IN + tile * 64];
            #pragma unroll
            for (int kk = 0; kk < 64; kk += 4) {
                float4 x0 = xr0[kk >> 2];
                float4 x1 = xr1[kk >> 2];
                float4 x2 = xr2[kk >> 2];
                float4 x3 = xr3[kk >> 2];
                float w0 = wt[(kk + 0) * 64 + c];
                float w1 = wt[(kk + 1) * 64 + c];
                float w2 = wt[(kk + 2) * 64 + c];
                float w3 = wt[(kk + 3) * 64 + c];
                a0 += x0.x * w0 + x0.y * w1 + x0.z * w2 + x0.w * w3;
                a1 += x1.x * w0 + x1.y * w1 + x1.z * w2 + x1.w * w3;
                a2 += x2.x * w0 + x2.y * w1 + x2.z * w2 + x2.w * w3;
                a3 += x3.x * w0 + x3.y * w1 + x3.z * w2 + x3.w * w3;
            }
            __syncthreads();                 // all reads of wt done
            if (tile < 7) {
                wtv[t] = pf0; wtv[t + 256] = pf1;
                wtv[t + 512] = pf2; wtv[t + 768] = pf3;
            }
        }
        // epilogue: h1 + fused es/ed for the 4 rows
        float acc[4] = {a0, a1, a2, a3};
        #pragma unroll
        for (int r = 0; r < 4; ++r) {
            const int n = row0 + wv + 4 * r;
            h1[(size_t)n * F1 + c] = acc[r];
            float s = acc[r] * asrc[c];
            float d = acc[r] * adst[c];
            s += __shfl_xor(s, 1); s += __shfl_xor(s, 2); s += __shfl_xor(s, 4);
            d += __shfl_xor(d, 1); d += __shfl_xor(d, 2); d += __shfl_xor(d, 4);
            if ((c & 7) == 0) {
                es[n * NH1 + (c >> 3)] = s;
                ed[n * NH1 + (c >> 3)] = d;
            }
        }
    } else {
        // ---- CSR scan: one wave per row; width derived per-wave ----
        const int w = detect_width_wave(adj, l);
        const int row = (blockIdx.x - GEMM_BLKS) * 4 + wv;
        int* cnt = scnt + wv;
        if (l == 0) *cnt = 0;              // same-wave DS ops are in-order
        unsigned short* outp = neigh + (size_t)row * MAXDEG;
        if (w == 1) {
            const uint4* p = (const uint4*)(adj + (size_t)row * N_NODES);
            uint4 v[4];
            #pragma unroll
            for (int i = 0; i < 4; ++i) v[i] = p[l + 64 * i];   // 4 loads in flight
            #pragma unroll
            for (int i = 0; i < 4; ++i) {
                if ((v[i].x | v[i].y | v[i].z | v[i].w) == 0u) continue;
                unsigned int wd[4] = {v[i].x, v[i].y, v[i].z, v[i].w};
                int base = (l + 64 * i) * 16;
                for (int q = 0; q < 4; ++q) {
                    unsigned int word = wd[q];
                    for (int bb = 0; bb < 4; ++bb) {
                        if ((word >> (8 * bb)) & 0xffu) {
                            int pos = atomicAdd(cnt, 1);
                            if (pos < MAXDEG) outp[pos] = (unsigned short)(base + q * 4 + bb);
                        }
                    }
                }
            }
        } else if (w == 2) {
            const uint4* p = (const uint4*)(adj + (size_t)row * N_NODES * 2);
            uint4 v[8];
            #pragma unroll
            for (int i = 0; i < 8; ++i) v[i] = p[l + 64 * i];
            #pragma unroll
            for (int i = 0; i < 8; ++i) {
                if ((v[i].x | v[i].y | v[i].z | v[i].w) == 0u) continue;
                unsigned int wd[4] = {v[i].x, v[i].y, v[i].z, v[i].w};
                int base = (l + 64 * i) * 8;
                for (int q = 0; q < 4; ++q) {
                    unsigned int word = wd[q];
                    if (word & 0xffffu) {
                        int pos = atomicAdd(cnt, 1);
                        if (pos < MAXDEG) outp[pos] = (unsigned short)(base + q * 2);
                    }
                    if (word >> 16) {
                        int pos = atomicAdd(cnt, 1);
                        if (pos < MAXDEG) outp[pos] = (unsigned short)(base + q * 2 + 1);
                    }
                }
            }
        } else {
            const uint4* p = (const uint4*)(adj + (size_t)row * N_NODES * 4);
            #pragma unroll
            for (int b = 0; b < 2; ++b) {
                uint4 v[8];
                #pragma unroll
                for (int i = 0; i < 8; ++i) v[i] = p[l + 64 * (b * 8 + i)];
                #pragma unroll
                for (int i = 0; i < 8; ++i) {
                    if ((v[i].x | v[i].y | v[i].z | v[i].w) == 0u) continue;
                    unsigned int wd[4] = {v[i].x, v[i].y, v[i].z, v[i].w};
                    int base = (l + 64 * (b * 8 + i)) * 4;
                    for (int q = 0; q < 4; ++q) {
                        if (wd[q]) {
                            int pos = atomicAdd(cnt, 1);
                            if (pos < MAXDEG) outp[pos] = (unsigned short)(base + q);
                        }
                    }
                }
            }
        }
        if (l == 0) deg[row] = min(*cnt, MAXDEG);   // same-wave read-after-atomic
    }
}

// ---------------------------------------------------------------------------
// Attention layer 1 + ELU + fused gemm2/scores2. Per-wave, no block barriers.
// Neighbor ids loaded straight from `neigh` (coalesced 128 B/trip) and
// broadcast via __shfl in the PV loop — the LDS list is gone; only the
// genuine lane->slot transpose buffer `pw` remains in LDS.
// ---------------------------------------------------------------------------
__global__ __launch_bounds__(256) void attn1_kernel(
        const unsigned short* __restrict__ neigh, const int* __restrict__ deg,
        const float* __restrict__ h1, const float* __restrict__ es,
        const float* __restrict__ ed, const float* __restrict__ W2,
        const float* __restrict__ a2s, const float* __restrict__ a2d,
        float* __restrict__ h2, float* __restrict__ es2, float* __restrict__ ed2) {
    __shared__ float pbufA[4 * 576];
    __shared__ float arowA[4 * 64];
    const int t = threadIdx.x;
    const int wv = t >> 6;
    const int l = t & 63;
    const int i = blockIdx.x * 4 + wv;
    float* pw   = pbufA + wv * 576;
    float* arow = arowA + wv * 64;
    const int hq = l >> 3;

    const int K = deg[i];
    const unsigned short* lst = neigh + (size_t)i * MAXDEG;

    float plsum[NH1];
    #pragma unroll
    for (int h = 0; h < NH1; ++h) plsum[h] = 0.f;
    const float4 e0 = *(const float4*)(es + (size_t)i * NH1);
    const float4 e1 = *(const float4*)(es + (size_t)i * NH1 + 4);
    const float esi[NH1] = {e0.x, e0.y, e0.z, e0.w, e1.x, e1.y, e1.z, e1.w};
    float acc = 0.f;

    for (int t0 = 0; t0 < K; t0 += 64) {
        const int tc = min(64, K - t0);
        const bool valid = l < tc;
        const int j = valid ? (int)lst[t0 + l] : 0;   // beyond-deg entries are poison
        const float4 d0v = *(const float4*)(ed + (size_t)j * NH1);
        const float4 d1v = *(const float4*)(ed + (size_t)j * NH1 + 4);
        const float edv[NH1] = {d0v.x, d0v.y, d0v.z, d0v.w,
                                d1v.x, d1v.y, d1v.z, d1v.w};
        #pragma unroll
        for (int h = 0; h < NH1; ++h) {
            float v = esi[h] + edv[h];
            v = (v >= 0.f) ? v : 0.2f * v;      // LeakyReLU(0.2)
            float p = valid ? __expf(v) : 0.f;  // no max-shift: |v|<~4
            plsum[h] += p;
            pw[l * 9 + h] = p;
        }
        __builtin_amdgcn_wave_barrier();
        const int tcPad = (tc + 7) & ~7;
        for (int u = 0; u < tcPad; u += 8) {
            #pragma unroll
            for (int vv = 0; vv < 8; ++vv) {
                const int slot = u + vv;
                const int jn = __shfl(j, slot);     // broadcast neighbor id
                acc += pw[slot * 9 + hq] * h1[(size_t)jn * F1 + l];
            }
        }
        __builtin_amdgcn_wave_barrier();
    }
    float lsum[NH1];
    #pragma unroll
    for (int h = 0; h < NH1; ++h) lsum[h] = wave_sum(plsum[h]);
    float o = acc / lsum[hq];
    float a1v = (o > 0.f) ? o : (__expf(o) - 1.f);  // ELU

    // fused gemm2 + scores2 (row-local, per-wave)
    arow[l] = a1v;
    __builtin_amdgcn_wave_barrier();
    const int cc = l & 15;
    const int kg = l >> 4;
    float hacc = 0.f;
    #pragma unroll
    for (int k = 0; k < 16; ++k)
        hacc += arow[kg * 16 + k] * W2[(kg * 16 + k) * C2 + cc];
    hacc += __shfl_xor(hacc, 16);
    hacc += __shfl_xor(hacc, 32);
    if (l < C2) h2[(size_t)i * C2 + l] = hacc;
    float s2 = hacc * a2s[cc];
    float d2 = hacc * a2d[cc];
    s2 += __shfl_xor(s2, 1); s2 += __shfl_xor(s2, 2);
    s2 += __shfl_xor(s2, 4); s2 += __shfl_xor(s2, 8);
    d2 += __shfl_xor(d2, 1); d2 += __shfl_xor(d2, 2);
    d2 += __shfl_xor(d2, 4); d2 += __shfl_xor(d2, 8);
    if (l == 0) { es2[i] = s2; ed2[i] = d2; }
}

// ---------------------------------------------------------------------------
// Attention layer 2 — LDS-free: neighbor ids and p broadcast via __shfl.
// ---------------------------------------------------------------------------
__global__ __launch_bounds__(256) void attn2_kernel(
        const unsigned short* __restrict__ neigh, const int* __restrict__ deg,
        const float* __restrict__ h2, const float* __restrict__ es2,
        const float* __restrict__ ed2, float* __restrict__ out) {
    const int t = threadIdx.x;
    const int wv = t >> 6;
    const int l = t & 63;
    const int i = blockIdx.x * 4 + wv;
    const int c = l & 15;
    const int g = l >> 4;

    const int K = deg[i];
    const unsigned short* lst = neigh + (size_t)i * MAXDEG;

    float plsum = 0.f, acc = 0.f;
    const float esi = es2[i];
    for (int t0 = 0; t0 < K; t0 += 64) {
        const int tc = min(64, K - t0);
        const bool valid = l < tc;
        const int j = valid ? (int)lst[t0 + l] : 0;
        float v = esi + ed2[j];
        v = (v >= 0.f) ? v : 0.2f * v;
        float p = valid ? __expf(v) : 0.f;   // no max-shift
        plsum += p;
        const int tcPad = (tc + 3) & ~3;
        for (int u = g; u < tcPad; u += 4) {
            const int jn = __shfl(j, u);     // per-group broadcast
            const float pv = __shfl(p, u);
            acc += pv * h2[(size_t)jn * C2 + c];
        }
    }
    float lsum = wave_sum(plsum);    // wave-uniform
    acc += __shfl_xor(acc, 16);
    acc += __shfl_xor(acc, 32);
    if (l < C2) out[(size_t)i * C2 + l] = acc / lsum;
}

extern "C" void kernel_launch(void* const* d_in, const int* in_sizes, int n_in,
                              void* d_out, int out_size, void* d_ws, size_t ws_size,
                              hipStream_t stream) {
    const float* x           = (const float*)d_in[0];
    const unsigned char* adj = (const unsigned char*)d_in[1];
    const float* W1          = (const float*)d_in[2];
    const float* a1src       = (const float*)d_in[3];
    const float* a1dst       = (const float*)d_in[4];
    const float* W2          = (const float*)d_in[5];
    const float* a2src       = (const float*)d_in[6];
    const float* a2dst       = (const float*)d_in[7];
    float* out = (float*)d_out;

    // workspace layout (~2.6 MB), all offsets 256B-aligned
    char* ws = (char*)d_ws;
    size_t off = 0;
    off += 256;                                       // (reserved)
    unsigned short* neigh = (unsigned short*)(ws + off);
    off += (size_t)N_NODES * MAXDEG * 2;              // 1 MB
    int* deg = (int*)(ws + off);                      off += (size_t)N_NODES * 4;
    float* h1 = (float*)(ws + off);                   off += (size_t)N_NODES * F1 * 4;
    float* es1 = (float*)(ws + off);                  off += (size_t)N_NODES * NH1 * 4;
    float* ed1 = (float*)(ws + off);                  off += (size_t)N_NODES * NH1 * 4;
    float* h2 = (float*)(ws + off);                   off += (size_t)N_NODES * C2 * 4;
    float* es2 = (float*)(ws + off);                  off += (size_t)N_NODES * 4;
    float* ed2 = (float*)(ws + off);                  off += (size_t)N_NODES * 4;

    hipLaunchKernelGGL(frontend_kernel, dim3(GEMM_BLKS + SCAN_BLKS), dim3(256), 0, stream,
                       adj, neigh, deg, x, W1, a1src, a1dst, h1, es1, ed1);
    hipLaunchKernelGGL(attn1_kernel, dim3(N_NODES / 4), dim3(256), 0, stream,
                       neigh, deg, h1, es1, ed1, W2, a2src, a2dst, h2, es2, ed2);
    hipLaunchKernelGGL(attn2_kernel, dim3(N_NODES / 4), dim3(256), 0, stream,
                       neigh, deg, h2, es2, ed2, out);
}